// Round 8
// baseline (207.783 us; speedup 1.0000x reference)
//
#include <hip/hip_runtime.h>

// SpikeDrivenTransformer block, MI355X. T=4 B=16 C=512 H=W=16 (N=256), HEADS=8.
// ALL inputs/outputs fp32. Post-LIF tensors are binary -> conv1x1 = sparse
// column-sums over an active-channel list (scalarized via readfirstlane).
// R8: split-list parallelism. k2 = 768 thr (2 list-halves x 384), k4 = 512 thr
// (2 list-halves x 2 cols x 128). Partial accs combined via LDS. Inner bodies
// identical to R7. prep/k5 unchanged.

#define T_  4
#define B_  16
#define C_  512
#define N_  256
#define O3_ 1536
#define EPS_ 1e-5f

typedef unsigned int uint32;

// ---------------- prep: weight transposes + BN fold + x-LIF + counter zero ----
__global__ void k_prep(const float* __restrict__ qw, const float* __restrict__ kw,
                       const float* __restrict__ vw, const float* __restrict__ pw,
                       const float* qg,const float* qb,const float* qm,const float* qv,
                       const float* kg,const float* kb,const float* km,const float* kvr,
                       const float* vg,const float* vb,const float* vm,const float* vv,
                       const float* pg,const float* pb2,const float* pm,const float* pv,
                       const float* projb, const float* __restrict__ x,
                       float* __restrict__ wqkv_t, float* __restrict__ pwt,
                       float* __restrict__ bnc, uint32* __restrict__ xs_mask32,
                       uint32* __restrict__ cnt32){
    __shared__ float tile[64 * 65];
    __shared__ uint32 sm32[64 * 17];
    int bx = blockIdx.x, tid = threadIdx.x;
    if (bx < 256) {
        const float* src; float* dst; int ocol;
        int tl;
        if (bx < 192) { int g = bx / 64; tl = bx % 64;
            src = (g == 0) ? qw : (g == 1) ? kw : vw;
            dst = wqkv_t; ocol = g * 512;
        } else { tl = bx - 192; src = pw; dst = pwt; ocol = 0; }
        int o0 = (tl >> 3) * 64, c0 = (tl & 7) * 64;
        int dstride = (bx < 192) ? O3_ : C_;
        #pragma unroll
        for (int i = 0; i < 16; i++) {
            int idx = i * 256 + tid;
            int cl = idx & 63, ol = idx >> 6;
            tile[ol * 65 + cl] = src[(size_t)(o0 + ol) * C_ + c0 + cl];
        }
        __syncthreads();
        #pragma unroll
        for (int i = 0; i < 16; i++) {
            int idx = i * 256 + tid;
            int ol = idx & 63, cl = idx >> 6;
            dst[(size_t)(c0 + cl) * dstride + ocol + o0 + ol] = tile[ol * 65 + cl];
        }
    } else if (bx < 258) {
        int ch = (bx - 256) * 256 + tid;
        if (ch < C_) {
            {   float inv = qg[ch] / sqrtf(qv[ch] + EPS_);
                bnc[ch] = inv;            bnc[512 + ch]  = qb[ch] - qm[ch] * inv; }
            {   float inv = kg[ch] / sqrtf(kvr[ch] + EPS_);
                bnc[1024 + ch] = inv;     bnc[1536 + ch] = kb[ch] - km[ch] * inv; }
            {   float inv = vg[ch] / sqrtf(vv[ch] + EPS_);
                bnc[2048 + ch] = inv;     bnc[2560 + ch] = vb[ch] - vm[ch] * inv; }
            {   float inv = pg[ch] / sqrtf(pv[ch] + EPS_);
                float shift = pb2[ch] - pm[ch] * inv;
                bnc[3072 + ch] = inv;     bnc[3584 + ch] = projb[ch] * inv + shift; }
        }
    } else if (bx < 770) {
        int r = bx - 258;
        int b = r >> 5, rem = r & 31;
        int c0 = (rem >> 2) * 64, n0 = (rem & 3) * 64;
        #pragma unroll
        for (int i = 0; i < 4; i++) {
            int idx = i * 256 + tid;
            int nq = idx & 15, cl = idx >> 4;
            const float* xp = x + ((size_t)b * C_ + c0 + cl) * N_ + n0 + nq * 4;
            float4 xv[4];
            #pragma unroll
            for (int t = 0; t < 4; t++)
                xv[t] = *reinterpret_cast<const float4*>(xp + (size_t)t * B_ * C_ * N_);
            uint32 packed = 0;
            #pragma unroll
            for (int e = 0; e < 4; e++) {
                float v = 0.f; unsigned m = 0;
                #pragma unroll
                for (int t = 0; t < 4; t++) {
                    float xt = reinterpret_cast<const float*>(&xv[t])[e];
                    v = v + (xt - v) * 0.5f;       // v += (x - v)/TAU, TAU=2
                    if (v - 1.0f >= 0.f) { m |= 1u << t; v = 0.f; }
                }
                packed |= m << (8 * e);
            }
            sm32[cl * 17 + nq] = packed;
        }
        __syncthreads();
        #pragma unroll
        for (int i = 0; i < 4; i++) {
            int idx = i * 256 + tid;
            int cq = idx & 15, nl = idx >> 4;
            uint32 outp = 0;
            #pragma unroll
            for (int e = 0; e < 4; e++) {
                uint32 wv = sm32[(cq * 4 + e) * 17 + (nl >> 2)];
                outp |= ((wv >> (8 * (nl & 3))) & 0xffu) << (8 * e);
            }
            xs_mask32[((size_t)b * N_ + n0 + nl) * 128 + (c0 >> 2) + cq] = outp;
        }
    } else {
        int idx = (bx - 770) * 256 + tid;          // 4096 uint32 counters
        cnt32[idx] = 0;
    }
}

// ---------------- k2: sparse qkv GEMM + BN + LIF + atomic kv counts ----------
// grid (N, B), block 768 = 2 list-halves x 384. Within a half: g=ltid>>7 (q/k/v),
// float4 slot = ltid (384 x 16B = 6KB row). Halves walk disjoint list ranges;
// partials combined via LDS.
__global__ __launch_bounds__(768) void
k2_qkv(const unsigned char* __restrict__ xs_mask,
       const float* __restrict__ wqkv_t,
       const float* __restrict__ bnc,
       unsigned char* __restrict__ q_mask,
       uint32* __restrict__ cnt32){
    __shared__ uint32 smask[128];                  // 512 B; reused as kbits buffer
    __shared__ uint32 scnt;
    __shared__ uint32 slist[512];
    __shared__ float  sacc[384 * 16];              // 24 KB partial-acc exchange
    int n = blockIdx.x, b = blockIdx.y, tid = threadIdx.x;
    int half = (tid >= 384);
    int ltid = half ? tid - 384 : tid;
    size_t colbase = ((size_t)b * N_ + n) * C_;
    if (tid < 128) smask[tid] = reinterpret_cast<const uint32*>(xs_mask + colbase)[tid];
    if (tid == 0) scnt = 0;
    __syncthreads();
    if (tid < 256) {
        const unsigned char* smb = (const unsigned char*)smask;
        #pragma unroll
        for (int h = 0; h < 2; h++) {
            int c = tid + (h << 8);
            unsigned m = smb[c];
            if (m) { unsigned p = atomicAdd(&scnt, 1u); slist[p] = (unsigned)c | (m << 16); }
        }
    }
    __syncthreads();
    int cnt = scnt;
    int mid = (cnt >> 1) & ~3;                     // multiple of 4
    int jbeg = half ? mid : 0;
    int jend = half ? cnt : mid;

    int g = ltid >> 7;                             // 0=q, 1=k, 2=v
    float acc[4][4];
    #pragma unroll
    for (int t = 0; t < 4; t++)
        #pragma unroll
        for (int i = 0; i < 4; i++) acc[t][i] = 0.f;

#define ACC4(t, w_) { acc[t][0]+=w_.x; acc[t][1]+=w_.y; acc[t][2]+=w_.z; acc[t][3]+=w_.w; }
    int j = jbeg;
    for (; j + 4 <= jend; j += 4) {
        unsigned e0 = __builtin_amdgcn_readfirstlane(slist[j]);
        unsigned e1 = __builtin_amdgcn_readfirstlane(slist[j + 1]);
        unsigned e2 = __builtin_amdgcn_readfirstlane(slist[j + 2]);
        unsigned e3 = __builtin_amdgcn_readfirstlane(slist[j + 3]);
        float4 w0 = reinterpret_cast<const float4*>(wqkv_t + (size_t)(e0 & 0xffffu) * O3_)[ltid];
        float4 w1 = reinterpret_cast<const float4*>(wqkv_t + (size_t)(e1 & 0xffffu) * O3_)[ltid];
        float4 w2 = reinterpret_cast<const float4*>(wqkv_t + (size_t)(e2 & 0xffffu) * O3_)[ltid];
        float4 w3 = reinterpret_cast<const float4*>(wqkv_t + (size_t)(e3 & 0xffffu) * O3_)[ltid];
        unsigned m0 = e0 >> 16, m1 = e1 >> 16, m2 = e2 >> 16, m3 = e3 >> 16;
        if (m0 & 1u) ACC4(0, w0)  if (m0 & 2u) ACC4(1, w0)
        if (m0 & 4u) ACC4(2, w0)  if (m0 & 8u) ACC4(3, w0)
        if (m1 & 1u) ACC4(0, w1)  if (m1 & 2u) ACC4(1, w1)
        if (m1 & 4u) ACC4(2, w1)  if (m1 & 8u) ACC4(3, w1)
        if (m2 & 1u) ACC4(0, w2)  if (m2 & 2u) ACC4(1, w2)
        if (m2 & 4u) ACC4(2, w2)  if (m2 & 8u) ACC4(3, w2)
        if (m3 & 1u) ACC4(0, w3)  if (m3 & 2u) ACC4(1, w3)
        if (m3 & 4u) ACC4(2, w3)  if (m3 & 8u) ACC4(3, w3)
    }
    for (; j < jend; j++) {
        unsigned e0 = __builtin_amdgcn_readfirstlane(slist[j]);
        float4 w0 = reinterpret_cast<const float4*>(wqkv_t + (size_t)(e0 & 0xffffu) * O3_)[ltid];
        unsigned m0 = e0 >> 16;
        if (m0 & 1u) ACC4(0, w0)  if (m0 & 2u) ACC4(1, w0)
        if (m0 & 4u) ACC4(2, w0)  if (m0 & 8u) ACC4(3, w0)
    }
#undef ACC4

    // combine halves through LDS
    if (half) {
        #pragma unroll
        for (int t = 0; t < 4; t++)
            #pragma unroll
            for (int i = 0; i < 4; i++) sacc[ltid * 16 + t * 4 + i] = acc[t][i];
    }
    __syncthreads();
    if (!half) {
        #pragma unroll
        for (int t = 0; t < 4; t++)
            #pragma unroll
            for (int i = 0; i < 4; i++) acc[t][i] += sacc[ltid * 16 + t * 4 + i];
    }

    // BN + LIF per owned channel (half 0 only); pack 4 channel-bytes into one uint.
    int chb = (ltid & 127) * 4;
    unsigned packed = 0;
    if (!half) {
        #pragma unroll
        for (int i = 0; i < 4; i++) {
            int ch = chb + i;
            float inv = bnc[g * 1024 + ch];
            float sh  = bnc[g * 1024 + 512 + ch];
            float v = 0.f; unsigned bits = 0;
            #pragma unroll
            for (int t = 0; t < 4; t++) {
                float pre = acc[t][i] * inv + sh;  // BN
                v = v + (pre - v) * 0.5f;          // LIF
                if (v - 1.0f >= 0.f) { bits |= 1u << t; v = 0.f; }
            }
            packed |= bits << (8 * i);
        }
        if (g == 0)      reinterpret_cast<uint32*>(q_mask + colbase)[ltid] = packed;
        else if (g == 1) smask[ltid - 128] = packed;   // kbits exchange
    }
    __syncthreads();
    if (!half && g == 2) {
        unsigned kb = smask[ltid - 256];
        unsigned kv = packed & kb;                 // 4 ch x 4 t-bits (byte each)
        if (kv) {
            uint32* cbase = cnt32 + b * 1024 + (chb >> 1);   // [b][t][c-pair]
            #pragma unroll
            for (int t = 0; t < 4; t++) {
                unsigned v01 = ((kv >> t) & 1u) | (((kv >> (8 + t)) & 1u) << 16);
                unsigned v23 = ((kv >> (16 + t)) & 1u) | (((kv >> (24 + t)) & 1u) << 16);
                if (v01) atomicAdd(cbase + t * 256, v01);
                if (v23) atomicAdd(cbase + t * 256 + 1, v23);
            }
        }
    }
}

// ---------------- k4: kv-LIF from counts + sparse proj GEMM + BN -------------
// grid (N/2, B), block 512 = 2 list-halves x (2 cols x 128). col=(tid>>7)&1,
// half=tid>>8, ctid=tid&127 (all wave-uniform splits).
__global__ __launch_bounds__(512) void
k4_attn_proj(const unsigned char* __restrict__ q_mask,
             const uint32* __restrict__ cnt32,
             const float* __restrict__ pwt,
             const float* __restrict__ bnc,
             float* __restrict__ y_t){
    __shared__ uint32 smask[2][128];
    __shared__ uint32 scnt[2];
    __shared__ uint32 slist[2][512];
    __shared__ float  sacc[256 * 16];              // 16 KB partial-acc exchange
    int b = blockIdx.y, tid = threadIdx.x;
    int half = tid >> 8, col = (tid >> 7) & 1, ctid = tid & 127;
    int n = blockIdx.x * 2 + col;
    size_t colbase = ((size_t)b * N_ + n) * C_;
    if (!half) {
        // recompute kv-LIF from integer counts (exact: halvings of ints)
        unsigned kvs_packed = 0;
        const uint32* cbase = cnt32 + b * 1024 + ctid * 2;
        uint32 c01[4], c23[4];
        #pragma unroll
        for (int t = 0; t < 4; t++) { c01[t] = cbase[t * 256]; c23[t] = cbase[t * 256 + 1]; }
        #pragma unroll
        for (int e = 0; e < 4; e++) {
            float v = 0.f; unsigned bits = 0;
            #pragma unroll
            for (int t = 0; t < 4; t++) {
                uint32 pair = (e < 2) ? c01[t] : c23[t];
                float cn = (float)(int)((e & 1) ? (pair >> 16) : (pair & 0xffffu));
                v = v + (cn - v) * 0.5f;
                if (v - 0.5f >= 0.f) { bits |= 1u << t; v = 0.f; }
            }
            kvs_packed |= bits << (8 * e);
        }
        uint32 qm = reinterpret_cast<const uint32*>(q_mask + colbase)[ctid];
        smask[col][ctid] = qm & kvs_packed;
        if (ctid == 0) scnt[col] = 0;
    }
    __syncthreads();
    if (!half) {
        const unsigned char* smb = (const unsigned char*)smask[col];
        #pragma unroll
        for (int h = 0; h < 4; h++) {
            int c = ctid * 4 + h;
            unsigned m = smb[c];
            if (m) { unsigned p = atomicAdd(&scnt[col], 1u); slist[col][p] = (unsigned)c | (m << 16); }
        }
    }
    __syncthreads();
    int cnt = scnt[col];
    const uint32* lst = slist[col];
    int mid = (cnt >> 1) & ~3;
    int jbeg = half ? mid : 0;
    int jend = half ? cnt : mid;

    float acc[4][4];
    #pragma unroll
    for (int t = 0; t < 4; t++)
        #pragma unroll
        for (int i = 0; i < 4; i++) acc[t][i] = 0.f;

#define ACC4(t, w_) { acc[t][0]+=w_.x; acc[t][1]+=w_.y; acc[t][2]+=w_.z; acc[t][3]+=w_.w; }
    int j = jbeg;
    for (; j + 4 <= jend; j += 4) {
        unsigned e0 = __builtin_amdgcn_readfirstlane(lst[j]);
        unsigned e1 = __builtin_amdgcn_readfirstlane(lst[j + 1]);
        unsigned e2 = __builtin_amdgcn_readfirstlane(lst[j + 2]);
        unsigned e3 = __builtin_amdgcn_readfirstlane(lst[j + 3]);
        float4 w0 = reinterpret_cast<const float4*>(pwt + (size_t)(e0 & 0xffffu) * C_)[ctid];
        float4 w1 = reinterpret_cast<const float4*>(pwt + (size_t)(e1 & 0xffffu) * C_)[ctid];
        float4 w2 = reinterpret_cast<const float4*>(pwt + (size_t)(e2 & 0xffffu) * C_)[ctid];
        float4 w3 = reinterpret_cast<const float4*>(pwt + (size_t)(e3 & 0xffffu) * C_)[ctid];
        unsigned m0 = e0 >> 16, m1 = e1 >> 16, m2 = e2 >> 16, m3 = e3 >> 16;
        if (m0 & 1u) ACC4(0, w0)  if (m0 & 2u) ACC4(1, w0)
        if (m0 & 4u) ACC4(2, w0)  if (m0 & 8u) ACC4(3, w0)
        if (m1 & 1u) ACC4(0, w1)  if (m1 & 2u) ACC4(1, w1)
        if (m1 & 4u) ACC4(2, w1)  if (m1 & 8u) ACC4(3, w1)
        if (m2 & 1u) ACC4(0, w2)  if (m2 & 2u) ACC4(1, w2)
        if (m2 & 4u) ACC4(2, w2)  if (m2 & 8u) ACC4(3, w2)
        if (m3 & 1u) ACC4(0, w3)  if (m3 & 2u) ACC4(1, w3)
        if (m3 & 4u) ACC4(2, w3)  if (m3 & 8u) ACC4(3, w3)
    }
    for (; j < jend; j++) {
        unsigned e0 = __builtin_amdgcn_readfirstlane(lst[j]);
        float4 w0 = reinterpret_cast<const float4*>(pwt + (size_t)(e0 & 0xffffu) * C_)[ctid];
        unsigned m0 = e0 >> 16;
        if (m0 & 1u) ACC4(0, w0)  if (m0 & 2u) ACC4(1, w0)
        if (m0 & 4u) ACC4(2, w0)  if (m0 & 8u) ACC4(3, w0)
    }
#undef ACC4

    // combine halves through LDS
    int slot = col * 128 + ctid;
    if (half) {
        #pragma unroll
        for (int t = 0; t < 4; t++)
            #pragma unroll
            for (int i = 0; i < 4; i++) sacc[slot * 16 + t * 4 + i] = acc[t][i];
    }
    __syncthreads();
    if (!half) {
        #pragma unroll
        for (int t = 0; t < 4; t++)
            #pragma unroll
            for (int i = 0; i < 4; i++) acc[t][i] += sacc[slot * 16 + t * 4 + i];

        float4 inv = reinterpret_cast<const float4*>(bnc + 3072)[ctid];
        float4 sh  = reinterpret_cast<const float4*>(bnc + 3584)[ctid];
        #pragma unroll
        for (int t = 0; t < 4; t++) {
            float4 y4;
            y4.x = acc[t][0] * inv.x + sh.x;
            y4.y = acc[t][1] * inv.y + sh.y;
            y4.z = acc[t][2] * inv.z + sh.z;
            y4.w = acc[t][3] * inv.w + sh.w;
            reinterpret_cast<float4*>(y_t + (((size_t)t * B_ + b) * N_ + n) * C_)[ctid] = y4;
        }
    }
}

// ---------------- k5: transpose back + identity add (float4 I/O) ----------------
// grid (B, C/64, N/64), block 256.
__global__ void k5_out(const float* __restrict__ y_t, const float* __restrict__ x,
                       float* __restrict__ out){
    __shared__ float tile[64 * 65];
    int b = blockIdx.x, o0 = blockIdx.y * 64, n0 = blockIdx.z * 64;
    int tid = threadIdx.x;
    for (int t = 0; t < T_; t++) {
        __syncthreads();
        #pragma unroll
        for (int i = 0; i < 4; i++) {
            int idx = i * 256 + tid;
            int o4 = idx & 15, nl = idx >> 4;
            float4 yv = *reinterpret_cast<const float4*>(
                y_t + (((size_t)t * B_ + b) * N_ + n0 + nl) * C_ + o0 + o4 * 4);
            tile[(o4 * 4 + 0) * 65 + nl] = yv.x;
            tile[(o4 * 4 + 1) * 65 + nl] = yv.y;
            tile[(o4 * 4 + 2) * 65 + nl] = yv.z;
            tile[(o4 * 4 + 3) * 65 + nl] = yv.w;
        }
        __syncthreads();
        #pragma unroll
        for (int i = 0; i < 4; i++) {
            int idx = i * 256 + tid;
            int n4 = idx & 15, ol = idx >> 4;
            size_t a = (((size_t)t * B_ + b) * C_ + o0 + ol) * N_ + n0 + n4 * 4;
            float4 xv = *reinterpret_cast<const float4*>(x + a);
            float4 yv;
            yv.x = tile[ol * 65 + n4 * 4 + 0] + xv.x;
            yv.y = tile[ol * 65 + n4 * 4 + 1] + xv.y;
            yv.z = tile[ol * 65 + n4 * 4 + 2] + xv.z;
            yv.w = tile[ol * 65 + n4 * 4 + 3] + xv.w;
            *reinterpret_cast<float4*>(out + a) = yv;
        }
    }
}

extern "C" void kernel_launch(void* const* d_in, const int* in_sizes, int n_in,
                              void* d_out, int out_size, void* d_ws, size_t ws_size,
                              hipStream_t stream){
    const float* x     = (const float*)d_in[0];
    const float* q_w   = (const float*)d_in[1];
    const float* q_g   = (const float*)d_in[2];
    const float* q_b   = (const float*)d_in[3];
    const float* q_m   = (const float*)d_in[4];
    const float* q_v   = (const float*)d_in[5];
    const float* k_w   = (const float*)d_in[6];
    const float* k_g   = (const float*)d_in[7];
    const float* k_b   = (const float*)d_in[8];
    const float* k_m   = (const float*)d_in[9];
    const float* k_v   = (const float*)d_in[10];
    const float* v_w   = (const float*)d_in[11];
    const float* v_g   = (const float*)d_in[12];
    const float* v_b   = (const float*)d_in[13];
    const float* v_m   = (const float*)d_in[14];
    const float* v_v   = (const float*)d_in[15];
    const float* pr_w  = (const float*)d_in[16];
    const float* pr_b  = (const float*)d_in[17];
    const float* p_g   = (const float*)d_in[18];
    const float* p_b2  = (const float*)d_in[19];
    const float* p_m   = (const float*)d_in[20];
    const float* p_v   = (const float*)d_in[21];
    float* out = (float*)d_out;

    char* ws = (char*)d_ws;
    float* wqkv_t          = (float*)(ws + 0);                 // 3,145,728
    float* pwt             = (float*)(ws + 3145728);           // 1,048,576
    float* bnc             = (float*)(ws + 4194304);           //    16,384
    unsigned char* xs_mask = (unsigned char*)(ws + 4210688);   // 2,097,152
    unsigned char* q_mask  = (unsigned char*)(ws + 6307840);   // 2,097,152
    uint32* cnt32          = (uint32*)(ws + 8404992);          //    16,384
    float* y_t             = (float*)(ws + 8421376);           // 33,554,432 -> ~42 MB

    hipLaunchKernelGGL(k_prep, dim3(786), dim3(256), 0, stream,
                       q_w, k_w, v_w, pr_w,
                       q_g,q_b,q_m,q_v, k_g,k_b,k_m,k_v, v_g,v_b,v_m,v_v,
                       p_g,p_b2,p_m,p_v, pr_b, x,
                       wqkv_t, pwt, bnc, (uint32*)xs_mask, cnt32);
    hipLaunchKernelGGL(k2_qkv, dim3(N_, B_), dim3(768), 0, stream,
                       xs_mask, wqkv_t, bnc, q_mask, cnt32);
    hipLaunchKernelGGL(k4_attn_proj, dim3(N_/2, B_), dim3(512), 0, stream,
                       q_mask, cnt32, pwt, bnc, y_t);
    hipLaunchKernelGGL(k5_out, dim3(B_, C_/64, N_/64), dim3(256), 0, stream, y_t, x, out);
}

// Round 9
// 201.846 us; speedup vs baseline: 1.0294x; 1.0294x over previous
//
#include <hip/hip_runtime.h>

// SpikeDrivenTransformer block, MI355X. T=4 B=16 C=512 H=W=16 (N=256), HEADS=8.
// ALL inputs/outputs fp32. Post-LIF tensors are binary -> conv1x1 = sparse
// column-sums over an active-channel list (scalarized via readfirstlane).
// R9: revert R8 split-list (k2/k4 back to R7-proven forms: bank-conflict-free,
// low LDS, VGPR 24). k5 gains a double-buffered t-loop (5 barriers vs 8).

#define T_  4
#define B_  16
#define C_  512
#define N_  256
#define O3_ 1536
#define EPS_ 1e-5f

typedef unsigned int uint32;

// ---------------- prep: weight transposes + BN fold + x-LIF + counter zero ----
__global__ void k_prep(const float* __restrict__ qw, const float* __restrict__ kw,
                       const float* __restrict__ vw, const float* __restrict__ pw,
                       const float* qg,const float* qb,const float* qm,const float* qv,
                       const float* kg,const float* kb,const float* km,const float* kvr,
                       const float* vg,const float* vb,const float* vm,const float* vv,
                       const float* pg,const float* pb2,const float* pm,const float* pv,
                       const float* projb, const float* __restrict__ x,
                       float* __restrict__ wqkv_t, float* __restrict__ pwt,
                       float* __restrict__ bnc, uint32* __restrict__ xs_mask32,
                       uint32* __restrict__ cnt32){
    __shared__ float tile[64 * 65];
    __shared__ uint32 sm32[64 * 17];
    int bx = blockIdx.x, tid = threadIdx.x;
    if (bx < 256) {
        const float* src; float* dst; int ocol;
        int tl;
        if (bx < 192) { int g = bx / 64; tl = bx % 64;
            src = (g == 0) ? qw : (g == 1) ? kw : vw;
            dst = wqkv_t; ocol = g * 512;
        } else { tl = bx - 192; src = pw; dst = pwt; ocol = 0; }
        int o0 = (tl >> 3) * 64, c0 = (tl & 7) * 64;
        int dstride = (bx < 192) ? O3_ : C_;
        #pragma unroll
        for (int i = 0; i < 16; i++) {
            int idx = i * 256 + tid;
            int cl = idx & 63, ol = idx >> 6;
            tile[ol * 65 + cl] = src[(size_t)(o0 + ol) * C_ + c0 + cl];
        }
        __syncthreads();
        #pragma unroll
        for (int i = 0; i < 16; i++) {
            int idx = i * 256 + tid;
            int ol = idx & 63, cl = idx >> 6;
            dst[(size_t)(c0 + cl) * dstride + ocol + o0 + ol] = tile[ol * 65 + cl];
        }
    } else if (bx < 258) {
        int ch = (bx - 256) * 256 + tid;
        if (ch < C_) {
            {   float inv = qg[ch] / sqrtf(qv[ch] + EPS_);
                bnc[ch] = inv;            bnc[512 + ch]  = qb[ch] - qm[ch] * inv; }
            {   float inv = kg[ch] / sqrtf(kvr[ch] + EPS_);
                bnc[1024 + ch] = inv;     bnc[1536 + ch] = kb[ch] - km[ch] * inv; }
            {   float inv = vg[ch] / sqrtf(vv[ch] + EPS_);
                bnc[2048 + ch] = inv;     bnc[2560 + ch] = vb[ch] - vm[ch] * inv; }
            {   float inv = pg[ch] / sqrtf(pv[ch] + EPS_);
                float shift = pb2[ch] - pm[ch] * inv;
                bnc[3072 + ch] = inv;     bnc[3584 + ch] = projb[ch] * inv + shift; }
        }
    } else if (bx < 770) {
        int r = bx - 258;
        int b = r >> 5, rem = r & 31;
        int c0 = (rem >> 2) * 64, n0 = (rem & 3) * 64;
        #pragma unroll
        for (int i = 0; i < 4; i++) {
            int idx = i * 256 + tid;
            int nq = idx & 15, cl = idx >> 4;
            const float* xp = x + ((size_t)b * C_ + c0 + cl) * N_ + n0 + nq * 4;
            float4 xv[4];
            #pragma unroll
            for (int t = 0; t < 4; t++)
                xv[t] = *reinterpret_cast<const float4*>(xp + (size_t)t * B_ * C_ * N_);
            uint32 packed = 0;
            #pragma unroll
            for (int e = 0; e < 4; e++) {
                float v = 0.f; unsigned m = 0;
                #pragma unroll
                for (int t = 0; t < 4; t++) {
                    float xt = reinterpret_cast<const float*>(&xv[t])[e];
                    v = v + (xt - v) * 0.5f;       // v += (x - v)/TAU, TAU=2
                    if (v - 1.0f >= 0.f) { m |= 1u << t; v = 0.f; }
                }
                packed |= m << (8 * e);
            }
            sm32[cl * 17 + nq] = packed;
        }
        __syncthreads();
        #pragma unroll
        for (int i = 0; i < 4; i++) {
            int idx = i * 256 + tid;
            int cq = idx & 15, nl = idx >> 4;
            uint32 outp = 0;
            #pragma unroll
            for (int e = 0; e < 4; e++) {
                uint32 wv = sm32[(cq * 4 + e) * 17 + (nl >> 2)];
                outp |= ((wv >> (8 * (nl & 3))) & 0xffu) << (8 * e);
            }
            xs_mask32[((size_t)b * N_ + n0 + nl) * 128 + (c0 >> 2) + cq] = outp;
        }
    } else {
        int idx = (bx - 770) * 256 + tid;          // 4096 uint32 counters
        cnt32[idx] = 0;
    }
}

// ---------------- k2: sparse qkv GEMM + BN + LIF + atomic kv counts ----------
// grid (N, B), block 384 (R7-proven). g=tid>>7 (q/k/v), thread owns 4 channels;
// one float4 per active row (384 lanes x 16B = full 6KB q|k|v row). Unroll-4.
__global__ __launch_bounds__(384) void
k2_qkv(const unsigned char* __restrict__ xs_mask,
       const float* __restrict__ wqkv_t,
       const float* __restrict__ bnc,
       unsigned char* __restrict__ q_mask,
       uint32* __restrict__ cnt32){
    __shared__ uint32 smask[128];                  // 512 bytes; reused as kbits buffer
    __shared__ uint32 scnt;
    __shared__ uint32 slist[512];
    int n = blockIdx.x, b = blockIdx.y, tid = threadIdx.x;
    size_t colbase = ((size_t)b * N_ + n) * C_;
    if (tid < 128) smask[tid] = reinterpret_cast<const uint32*>(xs_mask + colbase)[tid];
    if (tid == 0) scnt = 0;
    __syncthreads();
    if (tid < 256) {
        const unsigned char* smb = (const unsigned char*)smask;
        #pragma unroll
        for (int h = 0; h < 2; h++) {
            int c = tid + (h << 8);
            unsigned m = smb[c];
            if (m) { unsigned p = atomicAdd(&scnt, 1u); slist[p] = (unsigned)c | (m << 16); }
        }
    }
    __syncthreads();
    int cnt = scnt;

    int g = tid >> 7;                              // 0=q, 1=k, 2=v
    float acc[4][4];
    #pragma unroll
    for (int t = 0; t < 4; t++)
        #pragma unroll
        for (int i = 0; i < 4; i++) acc[t][i] = 0.f;

#define ACC4(t, w_) { acc[t][0]+=w_.x; acc[t][1]+=w_.y; acc[t][2]+=w_.z; acc[t][3]+=w_.w; }
    int j = 0;
    for (; j + 4 <= cnt; j += 4) {
        unsigned e0 = __builtin_amdgcn_readfirstlane(slist[j]);
        unsigned e1 = __builtin_amdgcn_readfirstlane(slist[j + 1]);
        unsigned e2 = __builtin_amdgcn_readfirstlane(slist[j + 2]);
        unsigned e3 = __builtin_amdgcn_readfirstlane(slist[j + 3]);
        float4 w0 = reinterpret_cast<const float4*>(wqkv_t + (size_t)(e0 & 0xffffu) * O3_)[tid];
        float4 w1 = reinterpret_cast<const float4*>(wqkv_t + (size_t)(e1 & 0xffffu) * O3_)[tid];
        float4 w2 = reinterpret_cast<const float4*>(wqkv_t + (size_t)(e2 & 0xffffu) * O3_)[tid];
        float4 w3 = reinterpret_cast<const float4*>(wqkv_t + (size_t)(e3 & 0xffffu) * O3_)[tid];
        unsigned m0 = e0 >> 16, m1 = e1 >> 16, m2 = e2 >> 16, m3 = e3 >> 16;
        if (m0 & 1u) ACC4(0, w0)  if (m0 & 2u) ACC4(1, w0)
        if (m0 & 4u) ACC4(2, w0)  if (m0 & 8u) ACC4(3, w0)
        if (m1 & 1u) ACC4(0, w1)  if (m1 & 2u) ACC4(1, w1)
        if (m1 & 4u) ACC4(2, w1)  if (m1 & 8u) ACC4(3, w1)
        if (m2 & 1u) ACC4(0, w2)  if (m2 & 2u) ACC4(1, w2)
        if (m2 & 4u) ACC4(2, w2)  if (m2 & 8u) ACC4(3, w2)
        if (m3 & 1u) ACC4(0, w3)  if (m3 & 2u) ACC4(1, w3)
        if (m3 & 4u) ACC4(2, w3)  if (m3 & 8u) ACC4(3, w3)
    }
    for (; j < cnt; j++) {
        unsigned e0 = __builtin_amdgcn_readfirstlane(slist[j]);
        float4 w0 = reinterpret_cast<const float4*>(wqkv_t + (size_t)(e0 & 0xffffu) * O3_)[tid];
        unsigned m0 = e0 >> 16;
        if (m0 & 1u) ACC4(0, w0)  if (m0 & 2u) ACC4(1, w0)
        if (m0 & 4u) ACC4(2, w0)  if (m0 & 8u) ACC4(3, w0)
    }
#undef ACC4

    // BN + LIF per owned channel; pack 4 channel-bytes into one uint.
    int chb = (tid & 127) * 4;
    unsigned packed = 0;
    #pragma unroll
    for (int i = 0; i < 4; i++) {
        int ch = chb + i;
        float inv = bnc[g * 1024 + ch];
        float sh  = bnc[g * 1024 + 512 + ch];
        float v = 0.f; unsigned bits = 0;
        #pragma unroll
        for (int t = 0; t < 4; t++) {
            float pre = acc[t][i] * inv + sh;      // BN
            v = v + (pre - v) * 0.5f;              // LIF
            if (v - 1.0f >= 0.f) { bits |= 1u << t; v = 0.f; }
        }
        packed |= bits << (8 * i);
    }
    if (g == 0)      reinterpret_cast<uint32*>(q_mask + colbase)[tid] = packed;
    else if (g == 1) smask[tid - 128] = packed;    // kbits exchange
    __syncthreads();
    if (g == 2) {
        unsigned kb = smask[tid - 256];
        unsigned kv = packed & kb;                 // 4 ch x 4 t-bits (byte each)
        if (kv) {
            uint32* cbase = cnt32 + b * 1024 + (chb >> 1);   // [b][t][c-pair]
            #pragma unroll
            for (int t = 0; t < 4; t++) {
                unsigned v01 = ((kv >> t) & 1u) | (((kv >> (8 + t)) & 1u) << 16);
                unsigned v23 = ((kv >> (16 + t)) & 1u) | (((kv >> (24 + t)) & 1u) << 16);
                if (v01) atomicAdd(cbase + t * 256, v01);
                if (v23) atomicAdd(cbase + t * 256 + 1, v23);
            }
        }
    }
}

// ---------------- k4: kv-LIF from counts + sparse proj GEMM + BN -------------
// grid (N/2, B), block 256 = 2 columns x 128 threads (col = tid>>7, wave-uniform).
// Thread owns 4 channels (float4 per 2KB row), unroll-4. (R7-proven.)
__global__ __launch_bounds__(256) void
k4_attn_proj(const unsigned char* __restrict__ q_mask,
             const uint32* __restrict__ cnt32,
             const float* __restrict__ pwt,
             const float* __restrict__ bnc,
             float* __restrict__ y_t){
    __shared__ uint32 smask[2][128];
    __shared__ uint32 scnt[2];
    __shared__ uint32 slist[2][512];
    int b = blockIdx.y, tid = threadIdx.x;
    int col = tid >> 7, ctid = tid & 127;
    int n = blockIdx.x * 2 + col;
    size_t colbase = ((size_t)b * N_ + n) * C_;
    // recompute kv-LIF from integer counts (exact: halvings of ints)
    unsigned kvs_packed = 0;
    {
        const uint32* cbase = cnt32 + b * 1024 + ctid * 2;
        uint32 c01[4], c23[4];
        #pragma unroll
        for (int t = 0; t < 4; t++) { c01[t] = cbase[t * 256]; c23[t] = cbase[t * 256 + 1]; }
        #pragma unroll
        for (int e = 0; e < 4; e++) {
            float v = 0.f; unsigned bits = 0;
            #pragma unroll
            for (int t = 0; t < 4; t++) {
                uint32 pair = (e < 2) ? c01[t] : c23[t];
                float cn = (float)(int)((e & 1) ? (pair >> 16) : (pair & 0xffffu));
                v = v + (cn - v) * 0.5f;
                if (v - 0.5f >= 0.f) { bits |= 1u << t; v = 0.f; }
            }
            kvs_packed |= bits << (8 * e);
        }
    }
    {
        uint32 qm = reinterpret_cast<const uint32*>(q_mask + colbase)[ctid];
        smask[col][ctid] = qm & kvs_packed;
    }
    if (ctid == 0) scnt[col] = 0;
    __syncthreads();
    {
        const unsigned char* smb = (const unsigned char*)smask[col];
        #pragma unroll
        for (int h = 0; h < 4; h++) {
            int c = ctid * 4 + h;
            unsigned m = smb[c];
            if (m) { unsigned p = atomicAdd(&scnt[col], 1u); slist[col][p] = (unsigned)c | (m << 16); }
        }
    }
    __syncthreads();
    int cnt = scnt[col];
    const uint32* lst = slist[col];

    float acc[4][4];
    #pragma unroll
    for (int t = 0; t < 4; t++)
        #pragma unroll
        for (int i = 0; i < 4; i++) acc[t][i] = 0.f;

#define ACC4(t, w_) { acc[t][0]+=w_.x; acc[t][1]+=w_.y; acc[t][2]+=w_.z; acc[t][3]+=w_.w; }
    int j = 0;
    for (; j + 4 <= cnt; j += 4) {
        unsigned e0 = __builtin_amdgcn_readfirstlane(lst[j]);
        unsigned e1 = __builtin_amdgcn_readfirstlane(lst[j + 1]);
        unsigned e2 = __builtin_amdgcn_readfirstlane(lst[j + 2]);
        unsigned e3 = __builtin_amdgcn_readfirstlane(lst[j + 3]);
        float4 w0 = reinterpret_cast<const float4*>(pwt + (size_t)(e0 & 0xffffu) * C_)[ctid];
        float4 w1 = reinterpret_cast<const float4*>(pwt + (size_t)(e1 & 0xffffu) * C_)[ctid];
        float4 w2 = reinterpret_cast<const float4*>(pwt + (size_t)(e2 & 0xffffu) * C_)[ctid];
        float4 w3 = reinterpret_cast<const float4*>(pwt + (size_t)(e3 & 0xffffu) * C_)[ctid];
        unsigned m0 = e0 >> 16, m1 = e1 >> 16, m2 = e2 >> 16, m3 = e3 >> 16;
        if (m0 & 1u) ACC4(0, w0)  if (m0 & 2u) ACC4(1, w0)
        if (m0 & 4u) ACC4(2, w0)  if (m0 & 8u) ACC4(3, w0)
        if (m1 & 1u) ACC4(0, w1)  if (m1 & 2u) ACC4(1, w1)
        if (m1 & 4u) ACC4(2, w1)  if (m1 & 8u) ACC4(3, w1)
        if (m2 & 1u) ACC4(0, w2)  if (m2 & 2u) ACC4(1, w2)
        if (m2 & 4u) ACC4(2, w2)  if (m2 & 8u) ACC4(3, w2)
        if (m3 & 1u) ACC4(0, w3)  if (m3 & 2u) ACC4(1, w3)
        if (m3 & 4u) ACC4(2, w3)  if (m3 & 8u) ACC4(3, w3)
    }
    for (; j < cnt; j++) {
        unsigned e0 = __builtin_amdgcn_readfirstlane(lst[j]);
        float4 w0 = reinterpret_cast<const float4*>(pwt + (size_t)(e0 & 0xffffu) * C_)[ctid];
        unsigned m0 = e0 >> 16;
        if (m0 & 1u) ACC4(0, w0)  if (m0 & 2u) ACC4(1, w0)
        if (m0 & 4u) ACC4(2, w0)  if (m0 & 8u) ACC4(3, w0)
    }
#undef ACC4

    float4 inv = reinterpret_cast<const float4*>(bnc + 3072)[ctid];
    float4 sh  = reinterpret_cast<const float4*>(bnc + 3584)[ctid];
    #pragma unroll
    for (int t = 0; t < 4; t++) {
        float4 y4;
        y4.x = acc[t][0] * inv.x + sh.x;
        y4.y = acc[t][1] * inv.y + sh.y;
        y4.z = acc[t][2] * inv.z + sh.z;
        y4.w = acc[t][3] * inv.w + sh.w;
        reinterpret_cast<float4*>(y_t + (((size_t)t * B_ + b) * N_ + n) * C_)[ctid] = y4;
    }
}

// ---------------- k5: transpose back + identity add (double-buffered t) -------
// grid (B, C/64, N/64), block 256. Two LDS tiles: load t+1 while storing t.
__global__ void k5_out(const float* __restrict__ y_t, const float* __restrict__ x,
                       float* __restrict__ out){
    __shared__ float tile[2][64 * 65];
    int b = blockIdx.x, o0 = blockIdx.y * 64, n0 = blockIdx.z * 64;
    int tid = threadIdx.x;

    // preload t=0
    #pragma unroll
    for (int i = 0; i < 4; i++) {
        int idx = i * 256 + tid;
        int o4 = idx & 15, nl = idx >> 4;
        float4 yv = *reinterpret_cast<const float4*>(
            y_t + (((size_t)0 * B_ + b) * N_ + n0 + nl) * C_ + o0 + o4 * 4);
        tile[0][(o4 * 4 + 0) * 65 + nl] = yv.x;
        tile[0][(o4 * 4 + 1) * 65 + nl] = yv.y;
        tile[0][(o4 * 4 + 2) * 65 + nl] = yv.z;
        tile[0][(o4 * 4 + 3) * 65 + nl] = yv.w;
    }
    __syncthreads();
    for (int t = 0; t < T_; t++) {
        int cur = t & 1, nxt = cur ^ 1;
        if (t + 1 < T_) {
            #pragma unroll
            for (int i = 0; i < 4; i++) {
                int idx = i * 256 + tid;
                int o4 = idx & 15, nl = idx >> 4;
                float4 yv = *reinterpret_cast<const float4*>(
                    y_t + (((size_t)(t + 1) * B_ + b) * N_ + n0 + nl) * C_ + o0 + o4 * 4);
                tile[nxt][(o4 * 4 + 0) * 65 + nl] = yv.x;
                tile[nxt][(o4 * 4 + 1) * 65 + nl] = yv.y;
                tile[nxt][(o4 * 4 + 2) * 65 + nl] = yv.z;
                tile[nxt][(o4 * 4 + 3) * 65 + nl] = yv.w;
            }
        }
        #pragma unroll
        for (int i = 0; i < 4; i++) {
            int idx = i * 256 + tid;
            int n4 = idx & 15, ol = idx >> 4;
            size_t a = (((size_t)t * B_ + b) * C_ + o0 + ol) * N_ + n0 + n4 * 4;
            float4 xv = *reinterpret_cast<const float4*>(x + a);
            float4 yv;
            yv.x = tile[cur][ol * 65 + n4 * 4 + 0] + xv.x;
            yv.y = tile[cur][ol * 65 + n4 * 4 + 1] + xv.y;
            yv.z = tile[cur][ol * 65 + n4 * 4 + 2] + xv.z;
            yv.w = tile[cur][ol * 65 + n4 * 4 + 3] + xv.w;
            *reinterpret_cast<float4*>(out + a) = yv;
        }
        __syncthreads();
    }
}

extern "C" void kernel_launch(void* const* d_in, const int* in_sizes, int n_in,
                              void* d_out, int out_size, void* d_ws, size_t ws_size,
                              hipStream_t stream){
    const float* x     = (const float*)d_in[0];
    const float* q_w   = (const float*)d_in[1];
    const float* q_g   = (const float*)d_in[2];
    const float* q_b   = (const float*)d_in[3];
    const float* q_m   = (const float*)d_in[4];
    const float* q_v   = (const float*)d_in[5];
    const float* k_w   = (const float*)d_in[6];
    const float* k_g   = (const float*)d_in[7];
    const float* k_b   = (const float*)d_in[8];
    const float* k_m   = (const float*)d_in[9];
    const float* k_v   = (const float*)d_in[10];
    const float* v_w   = (const float*)d_in[11];
    const float* v_g   = (const float*)d_in[12];
    const float* v_b   = (const float*)d_in[13];
    const float* v_m   = (const float*)d_in[14];
    const float* v_v   = (const float*)d_in[15];
    const float* pr_w  = (const float*)d_in[16];
    const float* pr_b  = (const float*)d_in[17];
    const float* p_g   = (const float*)d_in[18];
    const float* p_b2  = (const float*)d_in[19];
    const float* p_m   = (const float*)d_in[20];
    const float* p_v   = (const float*)d_in[21];
    float* out = (float*)d_out;

    char* ws = (char*)d_ws;
    float* wqkv_t          = (float*)(ws + 0);                 // 3,145,728
    float* pwt             = (float*)(ws + 3145728);           // 1,048,576
    float* bnc             = (float*)(ws + 4194304);           //    16,384
    unsigned char* xs_mask = (unsigned char*)(ws + 4210688);   // 2,097,152
    unsigned char* q_mask  = (unsigned char*)(ws + 6307840);   // 2,097,152
    uint32* cnt32          = (uint32*)(ws + 8404992);          //    16,384
    float* y_t             = (float*)(ws + 8421376);           // 33,554,432 -> ~42 MB

    hipLaunchKernelGGL(k_prep, dim3(786), dim3(256), 0, stream,
                       q_w, k_w, v_w, pr_w,
                       q_g,q_b,q_m,q_v, k_g,k_b,k_m,k_v, v_g,v_b,v_m,v_v,
                       p_g,p_b2,p_m,p_v, pr_b, x,
                       wqkv_t, pwt, bnc, (uint32*)xs_mask, cnt32);
    hipLaunchKernelGGL(k2_qkv, dim3(N_, B_), dim3(384), 0, stream,
                       xs_mask, wqkv_t, bnc, q_mask, cnt32);
    hipLaunchKernelGGL(k4_attn_proj, dim3(N_/2, B_), dim3(256), 0, stream,
                       q_mask, cnt32, pwt, bnc, y_t);
    hipLaunchKernelGGL(k5_out, dim3(B_, C_/64, N_/64), dim3(256), 0, stream, y_t, x, out);
}